// Round 10
// baseline (5103.132 us; speedup 1.0000x reference)
//
#include <hip/hip_runtime.h>
#include <math.h>

// Problem constants
#define NB 16      // batch
#define NE 128     // experts / channels
#define NK 8
#define HW 16384   // 128*128
#define NPIX (NB * HW)

// f32 transposed gate weights: gwT[e][f] = gate_w[f][e]
__device__ float g_gwT[NE * NE];

__global__ __launch_bounds__(256) void cvt_gw_kernel(const float* __restrict__ gate_w) {
    int i = blockIdx.x * 256 + threadIdx.x;   // i = e*128 + f
    if (i < NE * NE) {
        int e = i >> 7;
        int f = i & 127;
        g_gwT[i] = gate_w[f * NE + e];
    }
}

// load chunk K (8 float4 = 32 f-values) of channel CH into register buffer BUF
#define LOADC(BUF, CH, K)                                        \
    {                                                            \
        const float4* srcp = gq + (size_t)(CH) * 32 + (K) * 8;   \
        _Pragma("unroll")                                        \
        for (int j = 0; j < 8; ++j) BUF[j] = srcp[j];            \
    }

// FMA chunk K from BUF into acc[32K .. 32K+31]; exact ascending-f fmaf chain
#define FMAC(BUF, K, XE)                                         \
    {                                                            \
        _Pragma("unroll")                                        \
        for (int j = 0; j < 8; ++j) {                            \
            float4 g = BUF[j];                                   \
            const int f0 = (K) * 32 + 4 * j;                     \
            acc[f0 + 0] = fmaf(g.x, (XE), acc[f0 + 0]);          \
            acc[f0 + 1] = fmaf(g.y, (XE), acc[f0 + 1]);          \
            acc[f0 + 2] = fmaf(g.z, (XE), acc[f0 + 2]);          \
            acc[f0 + 3] = fmaf(g.w, (XE), acc[f0 + 3]);          \
        }                                                        \
    }

#define SGB_DS()   __builtin_amdgcn_sched_group_barrier(0x100, 8, 0)   // 8 DS_READ
#define SGB_VALU() __builtin_amdgcn_sched_group_barrier(0x002, 32, 0)  // 32 VALU

__global__ __launch_bounds__(256) void moe_kernel(const float* __restrict__ experts,
                                                  const float* __restrict__ gate_b,
                                                  float* __restrict__ out) {
    const int tid = threadIdx.x;
    const int p   = blockIdx.x * 256 + tid;          // pixel id
    const int n   = p >> 14;                         // /16384
    const int hw  = p & (HW - 1);

    const float* xp = experts + ((size_t)n * NE * HW + hw);   // channel stride HW

    // ---- one-time stage: gwT (64 KB) into LDS, bit-preserving ----
    __shared__ __align__(16) float gws[NE * NE];
    {
        const float4* src = (const float4*)g_gwT;
        float4* dst = (float4*)gws;
#pragma unroll
        for (int i = 0; i < 16; ++i) dst[tid + 256 * i] = src[tid + 256 * i];
    }
    __syncthreads();   // only barrier in the kernel

    float acc[NE];
#pragma unroll
    for (int f = 0; f < NE; ++f) acc[f] = 0.0f;

    const float4* gq = (const float4*)gws;   // channel ch = gq + ch*32

    // xe via 8-deep register rotation of coalesced global loads (proven)
    float xr[8], xn[8];
#pragma unroll
    for (int i = 0; i < 8; ++i) xr[i] = xp[(size_t)i * HW];

    // gw chunk ping-pong buffers (8 float4 each); WAR deps force depth-8 pipeline
    float4 A[8], B[8];
    LOADC(A, 0, 0);   // prologue: channel 0, chunk 0

    for (int g = 0; g < 16; ++g) {           // 16 groups of 8 channels
        if (g < 15) {                        // prefetch next x chunk (global, vmcnt)
            const float* xq = xp + (size_t)(g + 1) * 8 * HW;
#pragma unroll
            for (int i = 0; i < 8; ++i) xn[i] = xq[(size_t)i * HW];
        }
#pragma unroll
        for (int i = 0; i < 8; ++i) {
            const int ch = g * 8 + i;        // address math runtime; reg indices static
            const float xe = xr[i];
            LOADC(B, ch, 1);  SGB_DS();  FMAC(A, 0, xe);  SGB_VALU();
            LOADC(A, ch, 2);  SGB_DS();  FMAC(B, 1, xe);  SGB_VALU();
            LOADC(B, ch, 3);  SGB_DS();  FMAC(A, 2, xe);  SGB_VALU();
            if (i < 7) {
                LOADC(A, ch + 1, 0);  SGB_DS();
            } else if (g < 15) {
                LOADC(A, ch + 1, 0);  SGB_DS();     // next group's first channel
            }
            FMAC(B, 3, xe);  SGB_VALU();
        }
        if (g < 15) {
#pragma unroll
            for (int i = 0; i < 8; ++i) xr[i] = xn[i];
        }
    }

    // ---- + bias (zeros here; mirrored for fidelity) ----
#pragma unroll
    for (int f = 0; f < NE; ++f) acc[f] = acc[f] + gate_b[f];

    // ---- softmax, f32 numpy semantics (bit-frozen) ----
    float m = acc[0];
#pragma unroll
    for (int f = 1; f < NE; ++f) m = fmaxf(m, acc[f]);

    // correctly-rounded f32 exp of (l - m)
#pragma unroll
    for (int f = 0; f < NE; ++f) {
        acc[f] = (float)exp((double)(acc[f] - m));
    }

    // denominator: sequential ascending f32 sum (np strided-axis reduce order)
    float s = acc[0];
#pragma unroll
    for (int f = 1; f < NE; ++f) s = s + acc[f];

    // routing weights: IEEE f32 divide (ranking happens in w space -> mirror it)
#pragma unroll
    for (int f = 0; f < NE; ++f) acc[f] = acc[f] / s;

    // ---- top-8 on (w desc, idx asc): ascending-f insertion, strict '>' ----
    float t_v[NK];
    int   t_i[NK];
#pragma unroll
    for (int i = 0; i < NK; ++i) { t_v[i] = -1.0f; t_i[i] = 0; }

#pragma unroll
    for (int f = 0; f < NE; ++f) {
        float v  = acc[f];
        int   ix = f;
#pragma unroll
        for (int i = 0; i < NK; ++i) {
            bool gt = v > t_v[i];
            float tv = t_v[i]; int ti = t_i[i];
            t_v[i] = gt ? v  : tv;
            t_i[i] = gt ? ix : ti;
            v      = gt ? tv : v;
            ix     = gt ? ti : ix;
        }
    }

    // ---- gather + scale + write ----
    float* op = out + ((size_t)n * NK * HW + hw);
#pragma unroll
    for (int k = 0; k < NK; ++k) {
        float xv = xp[(size_t)t_i[k] * HW];
        op[(size_t)k * HW] = t_v[k] * xv;
    }
}

extern "C" void kernel_launch(void* const* d_in, const int* in_sizes, int n_in,
                              void* d_out, int out_size, void* d_ws, size_t ws_size,
                              hipStream_t stream) {
    // inputs: 0=x (unused), 1=experts [N,E,H,W] f32, 2=gate_w [E,E] f32, 3=gate_b [E] f32
    const float* experts = (const float*)d_in[1];
    const float* gate_w  = (const float*)d_in[2];
    const float* gate_b  = (const float*)d_in[3];
    float* out = (float*)d_out;

    hipLaunchKernelGGL(cvt_gw_kernel, dim3((NE * NE + 255) / 256), dim3(256), 0, stream, gate_w);
    hipLaunchKernelGGL(moe_kernel, dim3(NPIX / 256), dim3(256), 0, stream, experts, gate_b, out);
}